// Round 5
// baseline (293.786 us; speedup 1.0000x reference)
//
#include <hip/hip_runtime.h>
#include <math.h>

#define TILE 32
#define HALO 5
#define IH   42      // TILE + 2*HALO
#define LDSW 44      // sx/sy row stride (42 -> 44 floats, float4-aligned)
#define HBW  36      // hb row stride (32 -> 36 floats) -- round-0 layout:
                     // row-to-row delta 36 ≡ 4 (mod 32), half-wave delta
                     // 4*36 ≡ 16 -> full bank coverage, free 2-way only.

__global__ void zero_kernel(float* ws) {
    ws[0] = 0.0f;                 // partial-sum accumulator
    ((unsigned*)ws)[1] = 0u;      // block completion counter
}

// Round-0 proven structure + exactly the counter-validated diffs:
//  1) interior fast path in Stage A (r4: VALUBusy 51->26%, no spill)
//  2) fused finalize (r1-r4: absmax 0, saves one dispatch)
//  3) barrier restructure: A(c+1) and C(c) share one barrier region
//     (disjoint LDS: A writes sx/sy, C reads hb) -> 9 barriers -> 6,
//     global-load latency of A hidden under C's compute at wave level.
//     No register value lives across any barrier (r1-r3 spill lesson).
//  hb layout is round-0 verbatim (r4 lesson: pair-packing = 4-way conflict).
// LDS = 45056 B -> 3 blocks/CU; __launch_bounds__(256,3) -> VGPR cap ~170.
__global__ __launch_bounds__(256, 3) void ssim_kernel(
    const float* __restrict__ img1, const float* __restrict__ img2,
    const float* __restrict__ window, float* __restrict__ ws,
    float* __restrict__ out,
    int H, int W, float inv_n, unsigned nblocks)
{
    __shared__ float sx[IH][LDSW];
    __shared__ float sy[IH][LDSW];
    __shared__ float hb[5][IH][HBW];
    __shared__ float wsum[4];

    const int tid = threadIdx.x;
    const int x0  = blockIdx.x * TILE;
    const int y0  = blockIdx.y * TILE;

    // Recover separable 1D Gaussian: g[j] = w2d[5][j] / sqrt(w2d[5][5])
    float gr[11];
    {
        float inv = 1.0f / sqrtf(window[60]);
        #pragma unroll
        for (int t = 0; t < 11; ++t) gr[t] = window[55 + t] * inv;
    }

    // Stage A touches gx in [x0-5, x0+38], gh in [y0-5, y0+36].
    const bool interior = (x0 >= HALO) && (x0 + 39 <= W) &&
                          (y0 >= HALO) && (y0 + 37 <= H);

    // Stage A: load zero-padded input tile for channel c into sx/sy.
    // Load feeds the LDS store in the same loop body -- nothing persists.
    auto stage_a = [&](int c) {
        for (int item = tid; item < IH * 11; item += 256) {
            int r   = item / 11;
            int j4  = (item % 11) * 4;
            int gh  = y0 + r - HALO;
            int gx0 = x0 + j4 - HALO;
            float vx[4], vy[4];
            if (interior) {
                long base = ((long)gh * W + gx0) * 3 + c;   // HWC layout
                const float* p1 = img1 + base;
                const float* p2 = img2 + base;
                #pragma unroll
                for (int k = 0; k < 4; ++k) {
                    vx[k] = p1[k * 3];
                    vy[k] = p2[k * 3];
                }
            } else {
                bool rowok = ((unsigned)gh < (unsigned)H);
                #pragma unroll
                for (int k = 0; k < 4; ++k) {
                    int gx = gx0 + k;
                    bool ok = rowok && ((unsigned)gx < (unsigned)W);
                    long off = ((long)gh * W + gx) * 3 + c;
                    vx[k] = ok ? img1[off] : 0.0f;
                    vy[k] = ok ? img2[off] : 0.0f;
                }
            }
            *(float4*)&sx[r][j4] = make_float4(vx[0], vx[1], vx[2], vx[3]);
            *(float4*)&sy[r][j4] = make_float4(vy[0], vy[1], vy[2], vy[3]);
        }
    };

    float acc = 0.0f;

    stage_a(0);   // prologue: channel 0

    for (int c = 0; c < 3; ++c) {
        __syncthreads();   // sx/sy(c) visible; hb(c-1) readers done

        // ---------- Stage B: horizontal conv (5 quantities), 4 cols/thread ----------
        for (int item = tid; item < IH * 8; item += 256) {
            int r  = item >> 3;
            int j4 = (item & 7) * 4;
            float xv[16], yv[16];
            *(float4*)&xv[0]  = *(const float4*)&sx[r][j4];
            *(float4*)&xv[4]  = *(const float4*)&sx[r][j4 + 4];
            *(float4*)&xv[8]  = *(const float4*)&sx[r][j4 + 8];
            *(float4*)&xv[12] = *(const float4*)&sx[r][j4 + 12];
            *(float4*)&yv[0]  = *(const float4*)&sy[r][j4];
            *(float4*)&yv[4]  = *(const float4*)&sy[r][j4 + 4];
            *(float4*)&yv[8]  = *(const float4*)&sy[r][j4 + 8];
            *(float4*)&yv[12] = *(const float4*)&sy[r][j4 + 12];

            float xx[14], yy[14], xy[14];
            #pragma unroll
            for (int t = 0; t < 14; ++t) {
                xx[t] = xv[t] * xv[t];
                yy[t] = yv[t] * yv[t];
                xy[t] = xv[t] * yv[t];
            }
            float h0[4] = {0,0,0,0}, h1[4] = {0,0,0,0}, h2[4] = {0,0,0,0};
            float h3[4] = {0,0,0,0}, h4[4] = {0,0,0,0};
            #pragma unroll
            for (int jj = 0; jj < 4; ++jj) {
                #pragma unroll
                for (int t = 0; t < 11; ++t) {
                    float g = gr[t];
                    h0[jj] += g * xv[jj + t];
                    h1[jj] += g * yv[jj + t];
                    h2[jj] += g * xx[jj + t];
                    h3[jj] += g * yy[jj + t];
                    h4[jj] += g * xy[jj + t];
                }
            }
            *(float4*)&hb[0][r][j4] = make_float4(h0[0], h0[1], h0[2], h0[3]);
            *(float4*)&hb[1][r][j4] = make_float4(h1[0], h1[1], h1[2], h1[3]);
            *(float4*)&hb[2][r][j4] = make_float4(h2[0], h2[1], h2[2], h2[3]);
            *(float4*)&hb[3][r][j4] = make_float4(h3[0], h3[1], h3[2], h3[3]);
            *(float4*)&hb[4][r][j4] = make_float4(h4[0], h4[1], h4[2], h4[3]);
        }
        __syncthreads();   // hb(c) visible; sx/sy(c) readers done

        // ---------- A(c+1) ∥ C(c): disjoint LDS, one barrier region ----------
        if (c < 2) stage_a(c + 1);   // loads in flight under Stage C compute

        // ---------- Stage C: vertical conv + SSIM, 4 rows x 1 col per thread ----------
        {
            int j  = tid & 31;
            int i0 = (tid >> 5) * 4;
            float m1[4]  = {0,0,0,0}, m2[4]  = {0,0,0,0};
            float v11[4] = {0,0,0,0}, v22[4] = {0,0,0,0}, v12[4] = {0,0,0,0};
            #pragma unroll
            for (int t = 0; t < 14; ++t) {
                float b0 = hb[0][i0 + t][j];
                float b1 = hb[1][i0 + t][j];
                float b2 = hb[2][i0 + t][j];
                float b3 = hb[3][i0 + t][j];
                float b4 = hb[4][i0 + t][j];
                #pragma unroll
                for (int o = 0; o < 4; ++o) {
                    if (t - o >= 0 && t - o <= 10) {   // static after unroll
                        float g = gr[t - o];
                        m1[o]  += g * b0;
                        m2[o]  += g * b1;
                        v11[o] += g * b2;
                        v22[o] += g * b3;
                        v12[o] += g * b4;
                    }
                }
            }
            const float C1 = 0.0001f, C2 = 0.0009f;
            #pragma unroll
            for (int o = 0; o < 4; ++o) {
                int gy = y0 + i0 + o, gx = x0 + j;
                if (gy < H && gx < W) {
                    float mu1 = m1[o], mu2 = m2[o];
                    float mu11 = mu1 * mu1, mu22 = mu2 * mu2, mu12 = mu1 * mu2;
                    float s11 = v11[o] - mu11;
                    float s22 = v22[o] - mu22;
                    float s12 = v12[o] - mu12;
                    float num = (2.0f * mu12 + C1) * (2.0f * s12 + C2);
                    float den = (mu11 + mu22 + C1) * (s11 + s22 + C2);
                    acc += num / den;
                }
            }
        }
    }

    // ---------- block reduction + fused finalize ----------
    #pragma unroll
    for (int off = 32; off > 0; off >>= 1)
        acc += __shfl_down(acc, off, 64);
    int lane = tid & 63, wid = tid >> 6;
    if (lane == 0) wsum[wid] = acc;
    __syncthreads();
    if (tid == 0) {
        float bsum = wsum[0] + wsum[1] + wsum[2] + wsum[3];
        atomicAdd(ws, bsum);
        __threadfence();
        unsigned done = atomicAdd((unsigned*)ws + 1, 1u);
        if (done == nblocks - 1) {          // last block: all adds visible
            __threadfence();
            float s = atomicAdd(ws, 0.0f);  // atomic read of full sum
            out[0] = 1.0f - s * inv_n;
        }
    }
}

extern "C" void kernel_launch(void* const* d_in, const int* in_sizes, int n_in,
                              void* d_out, int out_size, void* d_ws, size_t ws_size,
                              hipStream_t stream) {
    const float* img1   = (const float*)d_in[0];
    const float* img2   = (const float*)d_in[1];
    const float* window = (const float*)d_in[2];
    float* out = (float*)d_out;
    float* ws  = (float*)d_ws;

    // Assume square image: in_sizes[0] = H*W*3
    long hw = (long)in_sizes[0] / 3;
    int W = (int)(sqrt((double)hw) + 0.5);
    int H = (int)(hw / W);

    float inv_n = (float)(1.0 / ((double)H * (double)W * 3.0));

    dim3 grid((W + TILE - 1) / TILE, (H + TILE - 1) / TILE);
    unsigned nblocks = grid.x * grid.y;

    zero_kernel<<<1, 1, 0, stream>>>(ws);
    ssim_kernel<<<grid, 256, 0, stream>>>(img1, img2, window, ws, out,
                                          H, W, inv_n, nblocks);
}

// Round 6
// 215.777 us; speedup vs baseline: 1.3615x; 1.3615x over previous
//
#include <hip/hip_runtime.h>
#include <math.h>

#define TILE 32
#define HALO 5
#define IH   42      // TILE + 2*HALO
#define LDSW 44      // padded input-tile row stride (42 -> 44 floats)
#define HBW  36      // padded hb row stride (32 -> 36 floats)

__global__ void zero_kernel(float* ws) { ws[0] = 0.0f; }

__global__ void finalize_kernel(const float* ws, float* out, float inv_n) {
    out[0] = 1.0f - ws[0] * inv_n;
}

// CONTROL EXPERIMENT (round 6): byte-for-byte the round-0 kernel that
// measured 134 us main-dispatch. Re-run to disambiguate code-caused
// regression (interior branch / fused finalize) from cross-session
// machine drift. No diffs vs round 0.
__global__ __launch_bounds__(256, 3) void ssim_kernel(
    const float* __restrict__ img1, const float* __restrict__ img2,
    const float* __restrict__ window, float* __restrict__ accum,
    int H, int W)
{
    __shared__ float sx[IH][LDSW];
    __shared__ float sy[IH][LDSW];
    __shared__ float hb[5][IH][HBW];
    __shared__ float wsum[4];

    const int tid = threadIdx.x;
    const int x0  = blockIdx.x * TILE;
    const int y0  = blockIdx.y * TILE;

    // Recover the separable 1D Gaussian from the 2D window:
    // w2d = outer(g,g) -> g[j] = w2d[5][j] / sqrt(w2d[5][5])
    float gr[11];
    {
        float inv = 1.0f / sqrtf(window[60]);     // window[5*11+5]
        #pragma unroll
        for (int t = 0; t < 11; ++t) gr[t] = window[55 + t] * inv;
    }

    float acc = 0.0f;

    for (int c = 0; c < 3; ++c) {
        __syncthreads();   // prev-iter Stage C (hb readers) done before Stage B rewrites hb

        // ---------- Stage A: load zero-padded input tile for channel c ----------
        for (int item = tid; item < IH * 11; item += 256) {
            int r   = item / 11;
            int j4  = (item % 11) * 4;
            int gh  = y0 + r - HALO;
            int gx0 = x0 + j4 - HALO;
            bool rowok = ((unsigned)gh < (unsigned)H);
            float vx[4], vy[4];
            #pragma unroll
            for (int k = 0; k < 4; ++k) {
                int gx = gx0 + k;
                bool ok = rowok && ((unsigned)gx < (unsigned)W);
                long off = ((long)gh * W + gx) * 3 + c;   // HWC layout
                vx[k] = ok ? img1[off] : 0.0f;
                vy[k] = ok ? img2[off] : 0.0f;
            }
            *(float4*)&sx[r][j4] = make_float4(vx[0], vx[1], vx[2], vx[3]);
            *(float4*)&sy[r][j4] = make_float4(vy[0], vy[1], vy[2], vy[3]);
        }
        __syncthreads();

        // ---------- Stage B: horizontal conv (5 quantities), 4 cols/thread ----------
        for (int item = tid; item < IH * 8; item += 256) {
            int r  = item >> 3;
            int j4 = (item & 7) * 4;
            float xv[16], yv[16];
            *(float4*)&xv[0]  = *(const float4*)&sx[r][j4];
            *(float4*)&xv[4]  = *(const float4*)&sx[r][j4 + 4];
            *(float4*)&xv[8]  = *(const float4*)&sx[r][j4 + 8];
            *(float4*)&xv[12] = *(const float4*)&sx[r][j4 + 12];
            *(float4*)&yv[0]  = *(const float4*)&sy[r][j4];
            *(float4*)&yv[4]  = *(const float4*)&sy[r][j4 + 4];
            *(float4*)&yv[8]  = *(const float4*)&sy[r][j4 + 8];
            *(float4*)&yv[12] = *(const float4*)&sy[r][j4 + 12];

            float xx[14], yy[14], xy[14];
            #pragma unroll
            for (int t = 0; t < 14; ++t) {
                xx[t] = xv[t] * xv[t];
                yy[t] = yv[t] * yv[t];
                xy[t] = xv[t] * yv[t];
            }
            float h0[4] = {0,0,0,0}, h1[4] = {0,0,0,0}, h2[4] = {0,0,0,0};
            float h3[4] = {0,0,0,0}, h4[4] = {0,0,0,0};
            #pragma unroll
            for (int jj = 0; jj < 4; ++jj) {
                #pragma unroll
                for (int t = 0; t < 11; ++t) {
                    float g = gr[t];
                    h0[jj] += g * xv[jj + t];
                    h1[jj] += g * yv[jj + t];
                    h2[jj] += g * xx[jj + t];
                    h3[jj] += g * yy[jj + t];
                    h4[jj] += g * xy[jj + t];
                }
            }
            *(float4*)&hb[0][r][j4] = make_float4(h0[0], h0[1], h0[2], h0[3]);
            *(float4*)&hb[1][r][j4] = make_float4(h1[0], h1[1], h1[2], h1[3]);
            *(float4*)&hb[2][r][j4] = make_float4(h2[0], h2[1], h2[2], h2[3]);
            *(float4*)&hb[3][r][j4] = make_float4(h3[0], h3[1], h3[2], h3[3]);
            *(float4*)&hb[4][r][j4] = make_float4(h4[0], h4[1], h4[2], h4[3]);
        }
        __syncthreads();

        // ---------- Stage C: vertical conv + SSIM, 4 rows/thread ----------
        {
            int j  = tid & 31;
            int i0 = (tid >> 5) * 4;
            float m1[4]  = {0,0,0,0}, m2[4]  = {0,0,0,0};
            float v11[4] = {0,0,0,0}, v22[4] = {0,0,0,0}, v12[4] = {0,0,0,0};
            #pragma unroll
            for (int t = 0; t < 14; ++t) {
                float b0 = hb[0][i0 + t][j];
                float b1 = hb[1][i0 + t][j];
                float b2 = hb[2][i0 + t][j];
                float b3 = hb[3][i0 + t][j];
                float b4 = hb[4][i0 + t][j];
                #pragma unroll
                for (int o = 0; o < 4; ++o) {
                    if (t - o >= 0 && t - o <= 10) {   // static after unroll
                        float g = gr[t - o];
                        m1[o]  += g * b0;
                        m2[o]  += g * b1;
                        v11[o] += g * b2;
                        v22[o] += g * b3;
                        v12[o] += g * b4;
                    }
                }
            }
            const float C1 = 0.0001f, C2 = 0.0009f;
            #pragma unroll
            for (int o = 0; o < 4; ++o) {
                int gy = y0 + i0 + o, gx = x0 + j;
                if (gy < H && gx < W) {
                    float mu1 = m1[o], mu2 = m2[o];
                    float mu11 = mu1 * mu1, mu22 = mu2 * mu2, mu12 = mu1 * mu2;
                    float s11 = v11[o] - mu11;
                    float s22 = v22[o] - mu22;
                    float s12 = v12[o] - mu12;
                    float num = (2.0f * mu12 + C1) * (2.0f * s12 + C2);
                    float den = (mu11 + mu22 + C1) * (s11 + s22 + C2);
                    acc += num / den;
                }
            }
        }
    }

    // ---------- block reduction ----------
    #pragma unroll
    for (int off = 32; off > 0; off >>= 1)
        acc += __shfl_down(acc, off, 64);
    int lane = tid & 63, wid = tid >> 6;
    if (lane == 0) wsum[wid] = acc;
    __syncthreads();
    if (tid == 0)
        atomicAdd(accum, wsum[0] + wsum[1] + wsum[2] + wsum[3]);
}

extern "C" void kernel_launch(void* const* d_in, const int* in_sizes, int n_in,
                              void* d_out, int out_size, void* d_ws, size_t ws_size,
                              hipStream_t stream) {
    const float* img1   = (const float*)d_in[0];
    const float* img2   = (const float*)d_in[1];
    const float* window = (const float*)d_in[2];
    float* out = (float*)d_out;
    float* ws  = (float*)d_ws;

    // Assume square image: in_sizes[0] = H*W*3
    long hw = (long)in_sizes[0] / 3;
    int W = (int)(sqrt((double)hw) + 0.5);
    int H = (int)(hw / W);

    float inv_n = (float)(1.0 / ((double)H * (double)W * 3.0));

    dim3 grid((W + TILE - 1) / TILE, (H + TILE - 1) / TILE);

    zero_kernel<<<1, 1, 0, stream>>>(ws);
    ssim_kernel<<<grid, 256, 0, stream>>>(img1, img2, window, ws, H, W);
    finalize_kernel<<<1, 1, 0, stream>>>(ws, out, inv_n);
}

// Round 7
// 207.416 us; speedup vs baseline: 1.4164x; 1.0403x over previous
//
#include <hip/hip_runtime.h>
#include <math.h>

#define TILEW 64
#define TILEH 32
#define HALO  5
#define IH    42     // TILEH + 2*HALO staged rows
#define SW    76     // sx/sy row stride = 19*4 (74 cols used + 2 pad)
#define NG    19     // float4 col-groups per staged row
#define HBW   64     // hb row stride: 16*4 -> Stage-B writes wave-linear
                     // (16 groups * 16B = 256B = row stride), Stage-C reads
                     // bank = j&31, 2-way only (free). No pad needed.

__global__ void zero_kernel(float* ws) { ws[0] = 0.0f; }

__global__ void finalize_kernel(const float* ws, float* out, float inv_n) {
    out[0] = 1.0f - ws[0] * inv_n;
}

// Round-7: 512-thread block, 64x32 tile. Single structural diff vs the
// 134us control (round 6): geometry. Inner bodies byte-identical.
//  - LDS 79.3KB -> 2 blocks/CU = 16 waves/CU (vs 12): +33% latency hiding
//  - 3 barriers/channel amortized over 2x pixels
//  - HBW=64 makes hb conflict-free on both write and read paths
// Stage A stays in the branchless ok?load:0 form (r4/r5 lesson: the
// wave-uniform interior branch serializes load batches, ~+75us).
// __launch_bounds__(512,4): 4 waves/EU -> 2 blocks/CU, VGPR cap 128 > ~84.
__global__ __launch_bounds__(512, 4) void ssim_kernel(
    const float* __restrict__ img1, const float* __restrict__ img2,
    const float* __restrict__ window, float* __restrict__ accum,
    int H, int W)
{
    __shared__ float sx[IH][SW];
    __shared__ float sy[IH][SW];
    __shared__ float hb[5][IH][HBW];
    __shared__ float wsum[8];

    const int tid = threadIdx.x;
    const int x0  = blockIdx.x * TILEW;
    const int y0  = blockIdx.y * TILEH;

    // Recover the separable 1D Gaussian from the 2D window:
    // w2d = outer(g,g) -> g[j] = w2d[5][j] / sqrt(w2d[5][5])
    float gr[11];
    {
        float inv = 1.0f / sqrtf(window[60]);     // window[5*11+5]
        #pragma unroll
        for (int t = 0; t < 11; ++t) gr[t] = window[55 + t] * inv;
    }

    float acc = 0.0f;

    for (int c = 0; c < 3; ++c) {
        __syncthreads();   // prev-iter Stage C (hb readers) done before Stage B rewrites hb

        // ---------- Stage A: load zero-padded input tile for channel c ----------
        // items = 42 rows x 19 col-groups = 798; branchless ok?load:0 form.
        for (int item = tid; item < IH * NG; item += 512) {
            int r   = item / NG;
            int j4  = (item % NG) * 4;
            int gh  = y0 + r - HALO;
            int gx0 = x0 + j4 - HALO;
            bool rowok = ((unsigned)gh < (unsigned)H);
            float vx[4], vy[4];
            #pragma unroll
            for (int k = 0; k < 4; ++k) {
                int gx = gx0 + k;
                bool ok = rowok && ((unsigned)gx < (unsigned)W);
                long off = ((long)gh * W + gx) * 3 + c;   // HWC layout
                vx[k] = ok ? img1[off] : 0.0f;
                vy[k] = ok ? img2[off] : 0.0f;
            }
            *(float4*)&sx[r][j4] = make_float4(vx[0], vx[1], vx[2], vx[3]);
            *(float4*)&sy[r][j4] = make_float4(vy[0], vy[1], vy[2], vy[3]);
        }
        __syncthreads();

        // ---------- Stage B: horizontal conv (5 quantities), 4 cols/thread ----------
        // items = 42 rows x 16 col-groups = 672.
        for (int item = tid; item < IH * 16; item += 512) {
            int r  = item >> 4;
            int j4 = (item & 15) * 4;
            float xv[16], yv[16];
            *(float4*)&xv[0]  = *(const float4*)&sx[r][j4];
            *(float4*)&xv[4]  = *(const float4*)&sx[r][j4 + 4];
            *(float4*)&xv[8]  = *(const float4*)&sx[r][j4 + 8];
            *(float4*)&xv[12] = *(const float4*)&sx[r][j4 + 12];
            *(float4*)&yv[0]  = *(const float4*)&sy[r][j4];
            *(float4*)&yv[4]  = *(const float4*)&sy[r][j4 + 4];
            *(float4*)&yv[8]  = *(const float4*)&sy[r][j4 + 8];
            *(float4*)&yv[12] = *(const float4*)&sy[r][j4 + 12];

            float xx[14], yy[14], xy[14];
            #pragma unroll
            for (int t = 0; t < 14; ++t) {
                xx[t] = xv[t] * xv[t];
                yy[t] = yv[t] * yv[t];
                xy[t] = xv[t] * yv[t];
            }
            float h0[4] = {0,0,0,0}, h1[4] = {0,0,0,0}, h2[4] = {0,0,0,0};
            float h3[4] = {0,0,0,0}, h4[4] = {0,0,0,0};
            #pragma unroll
            for (int jj = 0; jj < 4; ++jj) {
                #pragma unroll
                for (int t = 0; t < 11; ++t) {
                    float g = gr[t];
                    h0[jj] += g * xv[jj + t];
                    h1[jj] += g * yv[jj + t];
                    h2[jj] += g * xx[jj + t];
                    h3[jj] += g * yy[jj + t];
                    h4[jj] += g * xy[jj + t];
                }
            }
            *(float4*)&hb[0][r][j4] = make_float4(h0[0], h0[1], h0[2], h0[3]);
            *(float4*)&hb[1][r][j4] = make_float4(h1[0], h1[1], h1[2], h1[3]);
            *(float4*)&hb[2][r][j4] = make_float4(h2[0], h2[1], h2[2], h2[3]);
            *(float4*)&hb[3][r][j4] = make_float4(h3[0], h3[1], h3[2], h3[3]);
            *(float4*)&hb[4][r][j4] = make_float4(h4[0], h4[1], h4[2], h4[3]);
        }
        __syncthreads();

        // ---------- Stage C: vertical conv + SSIM, 4 rows x 1 col per thread ----------
        {
            int j  = tid & 63;
            int i0 = (tid >> 6) * 4;
            float m1[4]  = {0,0,0,0}, m2[4]  = {0,0,0,0};
            float v11[4] = {0,0,0,0}, v22[4] = {0,0,0,0}, v12[4] = {0,0,0,0};
            #pragma unroll
            for (int t = 0; t < 14; ++t) {
                float b0 = hb[0][i0 + t][j];
                float b1 = hb[1][i0 + t][j];
                float b2 = hb[2][i0 + t][j];
                float b3 = hb[3][i0 + t][j];
                float b4 = hb[4][i0 + t][j];
                #pragma unroll
                for (int o = 0; o < 4; ++o) {
                    if (t - o >= 0 && t - o <= 10) {   // static after unroll
                        float g = gr[t - o];
                        m1[o]  += g * b0;
                        m2[o]  += g * b1;
                        v11[o] += g * b2;
                        v22[o] += g * b3;
                        v12[o] += g * b4;
                    }
                }
            }
            const float C1 = 0.0001f, C2 = 0.0009f;
            #pragma unroll
            for (int o = 0; o < 4; ++o) {
                int gy = y0 + i0 + o, gx = x0 + j;
                if (gy < H && gx < W) {
                    float mu1 = m1[o], mu2 = m2[o];
                    float mu11 = mu1 * mu1, mu22 = mu2 * mu2, mu12 = mu1 * mu2;
                    float s11 = v11[o] - mu11;
                    float s22 = v22[o] - mu22;
                    float s12 = v12[o] - mu12;
                    float num = (2.0f * mu12 + C1) * (2.0f * s12 + C2);
                    float den = (mu11 + mu22 + C1) * (s11 + s22 + C2);
                    acc += num / den;
                }
            }
        }
    }

    // ---------- block reduction ----------
    #pragma unroll
    for (int off = 32; off > 0; off >>= 1)
        acc += __shfl_down(acc, off, 64);
    int lane = tid & 63, wid = tid >> 6;
    if (lane == 0) wsum[wid] = acc;
    __syncthreads();
    if (tid == 0) {
        float bsum = wsum[0] + wsum[1] + wsum[2] + wsum[3]
                   + wsum[4] + wsum[5] + wsum[6] + wsum[7];
        atomicAdd(accum, bsum);
    }
}

extern "C" void kernel_launch(void* const* d_in, const int* in_sizes, int n_in,
                              void* d_out, int out_size, void* d_ws, size_t ws_size,
                              hipStream_t stream) {
    const float* img1   = (const float*)d_in[0];
    const float* img2   = (const float*)d_in[1];
    const float* window = (const float*)d_in[2];
    float* out = (float*)d_out;
    float* ws  = (float*)d_ws;

    // Assume square image: in_sizes[0] = H*W*3
    long hw = (long)in_sizes[0] / 3;
    int W = (int)(sqrt((double)hw) + 0.5);
    int H = (int)(hw / W);

    float inv_n = (float)(1.0 / ((double)H * (double)W * 3.0));

    dim3 grid((W + TILEW - 1) / TILEW, (H + TILEH - 1) / TILEH);

    zero_kernel<<<1, 1, 0, stream>>>(ws);
    ssim_kernel<<<grid, 512, 0, stream>>>(img1, img2, window, ws, H, W);
    finalize_kernel<<<1, 1, 0, stream>>>(ws, out, inv_n);
}

// Round 9
// 206.758 us; speedup vs baseline: 1.4209x; 1.0032x over previous
//
#include <hip/hip_runtime.h>
#include <math.h>

#define TILEW 64
#define TILEH 32
#define HALO  5
#define IH    42     // TILEH + 2*HALO staged rows
#define SW    76     // sx/sy row stride = 19*4 -> Stage-A writes are exactly
                     // contiguous in item order (19 groups * 16B = 304B = row)
#define NG    19     // float4 col-groups per staged row
#define HBW   64     // hb row stride; Stage-C reads bank=j&31, 2-way (free)

__global__ void zero_kernel(float* ws) { ws[0] = 0.0f; }

__global__ void finalize_kernel(const float* ws, float* out, float inv_n) {
    out[0] = 1.0f - ws[0] * inv_n;
}

// Round-9 = round-8 kernel resubmitted verbatim (r8 bench was an infra
// failure: "container failed twice", no measurement taken).
// = round-7 geometry (125.5us, validated) + A(c+1)||C(c) overlap:
//   per channel: sync; B(c); sync; A(c+1); C(c)   (9 -> 6 barriers/block)
// A writes sx/sy, C reads hb -> disjoint LDS, race-free; B(c) finished
// reading sx/sy before the post-B sync, so A(c+1) may overwrite.
// Stage A stays branchless ok?load:0 (r4/r5 lesson: the wave-uniform
// interior branch serializes load batches, +75us). No register value
// lives across a barrier (r1-r3 spill lesson; tripwire = WRITE_SIZE).
__global__ __launch_bounds__(512, 4) void ssim_kernel(
    const float* __restrict__ img1, const float* __restrict__ img2,
    const float* __restrict__ window, float* __restrict__ accum,
    int H, int W)
{
    __shared__ float sx[IH][SW];
    __shared__ float sy[IH][SW];
    __shared__ float hb[5][IH][HBW];
    __shared__ float wsum[8];

    const int tid = threadIdx.x;
    const int x0  = blockIdx.x * TILEW;
    const int y0  = blockIdx.y * TILEH;

    // Recover the separable 1D Gaussian from the 2D window:
    // w2d = outer(g,g) -> g[j] = w2d[5][j] / sqrt(w2d[5][5])
    float gr[11];
    {
        float inv = 1.0f / sqrtf(window[60]);     // window[5*11+5]
        #pragma unroll
        for (int t = 0; t < 11; ++t) gr[t] = window[55 + t] * inv;
    }

    // Stage A: load zero-padded input tile for channel c into sx/sy.
    // Branchless; loads feed LDS stores in the same body, nothing persists.
    auto stage_a = [&](int c) {
        for (int item = tid; item < IH * NG; item += 512) {
            int r   = item / NG;
            int j4  = (item % NG) * 4;
            int gh  = y0 + r - HALO;
            int gx0 = x0 + j4 - HALO;
            bool rowok = ((unsigned)gh < (unsigned)H);
            float vx[4], vy[4];
            #pragma unroll
            for (int k = 0; k < 4; ++k) {
                int gx = gx0 + k;
                bool ok = rowok && ((unsigned)gx < (unsigned)W);
                long off = ((long)gh * W + gx) * 3 + c;   // HWC layout
                vx[k] = ok ? img1[off] : 0.0f;
                vy[k] = ok ? img2[off] : 0.0f;
            }
            *(float4*)&sx[r][j4] = make_float4(vx[0], vx[1], vx[2], vx[3]);
            *(float4*)&sy[r][j4] = make_float4(vy[0], vy[1], vy[2], vy[3]);
        }
    };

    float acc = 0.0f;

    stage_a(0);   // prologue: channel 0

    for (int c = 0; c < 3; ++c) {
        __syncthreads();   // sx/sy(c) visible; hb readers of prev channel done

        // ---------- Stage B: horizontal conv (5 quantities), 4 cols/thread ----------
        for (int item = tid; item < IH * 16; item += 512) {
            int r  = item >> 4;
            int j4 = (item & 15) * 4;
            float xv[16], yv[16];
            *(float4*)&xv[0]  = *(const float4*)&sx[r][j4];
            *(float4*)&xv[4]  = *(const float4*)&sx[r][j4 + 4];
            *(float4*)&xv[8]  = *(const float4*)&sx[r][j4 + 8];
            *(float4*)&xv[12] = *(const float4*)&sx[r][j4 + 12];
            *(float4*)&yv[0]  = *(const float4*)&sy[r][j4];
            *(float4*)&yv[4]  = *(const float4*)&sy[r][j4 + 4];
            *(float4*)&yv[8]  = *(const float4*)&sy[r][j4 + 8];
            *(float4*)&yv[12] = *(const float4*)&sy[r][j4 + 12];

            float xx[14], yy[14], xy[14];
            #pragma unroll
            for (int t = 0; t < 14; ++t) {
                xx[t] = xv[t] * xv[t];
                yy[t] = yv[t] * yv[t];
                xy[t] = xv[t] * yv[t];
            }
            float h0[4] = {0,0,0,0}, h1[4] = {0,0,0,0}, h2[4] = {0,0,0,0};
            float h3[4] = {0,0,0,0}, h4[4] = {0,0,0,0};
            #pragma unroll
            for (int jj = 0; jj < 4; ++jj) {
                #pragma unroll
                for (int t = 0; t < 11; ++t) {
                    float g = gr[t];
                    h0[jj] += g * xv[jj + t];
                    h1[jj] += g * yv[jj + t];
                    h2[jj] += g * xx[jj + t];
                    h3[jj] += g * yy[jj + t];
                    h4[jj] += g * xy[jj + t];
                }
            }
            *(float4*)&hb[0][r][j4] = make_float4(h0[0], h0[1], h0[2], h0[3]);
            *(float4*)&hb[1][r][j4] = make_float4(h1[0], h1[1], h1[2], h1[3]);
            *(float4*)&hb[2][r][j4] = make_float4(h2[0], h2[1], h2[2], h2[3]);
            *(float4*)&hb[3][r][j4] = make_float4(h3[0], h3[1], h3[2], h3[3]);
            *(float4*)&hb[4][r][j4] = make_float4(h4[0], h4[1], h4[2], h4[3]);
        }
        __syncthreads();   // hb(c) visible; sx/sy(c) readers (B) done

        // ---------- A(c+1) || C(c): disjoint LDS, shared barrier region ----------
        if (c < 2) stage_a(c + 1);   // HBM loads in flight under C's compute

        // ---------- Stage C: vertical conv + SSIM, 4 rows x 1 col per thread ----------
        {
            int j  = tid & 63;
            int i0 = (tid >> 6) * 4;
            float m1[4]  = {0,0,0,0}, m2[4]  = {0,0,0,0};
            float v11[4] = {0,0,0,0}, v22[4] = {0,0,0,0}, v12[4] = {0,0,0,0};
            #pragma unroll
            for (int t = 0; t < 14; ++t) {
                float b0 = hb[0][i0 + t][j];
                float b1 = hb[1][i0 + t][j];
                float b2 = hb[2][i0 + t][j];
                float b3 = hb[3][i0 + t][j];
                float b4 = hb[4][i0 + t][j];
                #pragma unroll
                for (int o = 0; o < 4; ++o) {
                    if (t - o >= 0 && t - o <= 10) {   // static after unroll
                        float g = gr[t - o];
                        m1[o]  += g * b0;
                        m2[o]  += g * b1;
                        v11[o] += g * b2;
                        v22[o] += g * b3;
                        v12[o] += g * b4;
                    }
                }
            }
            const float C1 = 0.0001f, C2 = 0.0009f;
            #pragma unroll
            for (int o = 0; o < 4; ++o) {
                int gy = y0 + i0 + o, gx = x0 + j;
                if (gy < H && gx < W) {
                    float mu1 = m1[o], mu2 = m2[o];
                    float mu11 = mu1 * mu1, mu22 = mu2 * mu2, mu12 = mu1 * mu2;
                    float s11 = v11[o] - mu11;
                    float s22 = v22[o] - mu22;
                    float s12 = v12[o] - mu12;
                    float num = (2.0f * mu12 + C1) * (2.0f * s12 + C2);
                    float den = (mu11 + mu22 + C1) * (s11 + s22 + C2);
                    acc += num / den;
                }
            }
        }
    }

    // ---------- block reduction ----------
    #pragma unroll
    for (int off = 32; off > 0; off >>= 1)
        acc += __shfl_down(acc, off, 64);
    int lane = tid & 63, wid = tid >> 6;
    if (lane == 0) wsum[wid] = acc;
    __syncthreads();
    if (tid == 0) {
        float bsum = wsum[0] + wsum[1] + wsum[2] + wsum[3]
                   + wsum[4] + wsum[5] + wsum[6] + wsum[7];
        atomicAdd(accum, bsum);
    }
}

extern "C" void kernel_launch(void* const* d_in, const int* in_sizes, int n_in,
                              void* d_out, int out_size, void* d_ws, size_t ws_size,
                              hipStream_t stream) {
    const float* img1   = (const float*)d_in[0];
    const float* img2   = (const float*)d_in[1];
    const float* window = (const float*)d_in[2];
    float* out = (float*)d_out;
    float* ws  = (float*)d_ws;

    // Assume square image: in_sizes[0] = H*W*3
    long hw = (long)in_sizes[0] / 3;
    int W = (int)(sqrt((double)hw) + 0.5);
    int H = (int)(hw / W);

    float inv_n = (float)(1.0 / ((double)H * (double)W * 3.0));

    dim3 grid((W + TILEW - 1) / TILEW, (H + TILEH - 1) / TILEH);

    zero_kernel<<<1, 1, 0, stream>>>(ws);
    ssim_kernel<<<grid, 512, 0, stream>>>(img1, img2, window, ws, H, W);
    finalize_kernel<<<1, 1, 0, stream>>>(ws, out, inv_n);
}